// Round 2
// baseline (483.767 us; speedup 1.0000x reference)
//
#include <hip/hip_runtime.h>

// AdaptiveGraph on MI355X — v2: no-LDS-staging restructure.
// K1 k_z  : Z = X W^T via bf16 MFMA hi/lo split; writes Zb [n][h] + ZbT [h][n]. (unchanged)
// K2 k_sv : per 32-row strip x 2048-col quarter: S^T tiles via MFMA with A/B frags read
//           DIRECTLY from L2-resident Zb/ZbT (no LDS staging, waves partition cols/h so
//           there is no intra-block reuse to exploit). relu -> rowsum partial; bf16(relu(S))
//           -> PT (double-buffered LDS, the only cross-wave data) -> V += PT @ Z.
//           1 barrier/iter, ~17 KB LDS, no atomics: V/rowsum quarter-partials plain-stored.
//           V partials live in the TAIL of the A buffer (k_a overwrites later).
// K3 k_out: out = (sum of 4 V partials) * rsinv.  (runs BEFORE k_a)
// K4 k_a  : zero-LDS zero-barrier A writer: direct-L2 A-frags, reg B-frags,
//           relu*rsinv, nontemporal float4 stores. Pure write-stream.

#define NR 8192
#define KD 256
#define HD 128

typedef short v8s __attribute__((ext_vector_type(8)));
typedef float v4f __attribute__((ext_vector_type(4)));

static __device__ __forceinline__ ushort f2bf(float f) {
    union { float f; unsigned u; } c; c.f = f;
    unsigned u = c.u;
    u += 0x7fffu + ((u >> 16) & 1u);  // RNE; inputs finite
    return (ushort)(u >> 16);
}
static __device__ __forceinline__ float bf2f(ushort b) {
    union { unsigned u; float f; } c; c.u = ((unsigned)b) << 16; return c.f;
}
// packed f32x2 -> bf16x2, RNE (matches f2bf)
static __device__ __forceinline__ unsigned cvtpk(float a, float b) {
    unsigned r;
    asm("v_cvt_pk_bf16_f32 %0, %1, %2" : "=v"(r) : "v"(a), "v"(b));
    return r;
}

// ---------------- K1: Z = X @ W^T (MFMA, hi/lo bf16 split) ----------------
__global__ __launch_bounds__(256) void k_z(const float* __restrict__ X,
                                           const float* __restrict__ W,
                                           ushort* __restrict__ Zb,
                                           ushort* __restrict__ ZbT) {
    __shared__ ushort Xhi[32][264];
    __shared__ ushort Xlo[32][264];
    int tid = threadIdx.x, lane = tid & 63, wave = tid >> 6;
    int lm = lane & 15, lq = lane >> 4;
    int n0 = blockIdx.x * 32;
    int hbase = wave * 32;
    v8s Whi[2][8], Wlo[2][8];
#pragma unroll
    for (int hi = 0; hi < 2; ++hi) {
        const float* wp = W + (hbase + hi * 16 + lm) * KD + lq * 8;
#pragma unroll
        for (int ks = 0; ks < 8; ++ks) {
            float4 w0 = *(const float4*)(wp + ks * 32);
            float4 w1 = *(const float4*)(wp + ks * 32 + 4);
            float wv[8] = {w0.x, w0.y, w0.z, w0.w, w1.x, w1.y, w1.z, w1.w};
#pragma unroll
            for (int j = 0; j < 8; ++j) {
                ushort h = f2bf(wv[j]);
                Whi[hi][ks][j] = (short)h;
                Wlo[hi][ks][j] = (short)f2bf(wv[j] - bf2f(h));
            }
        }
    }
#pragma unroll
    for (int t = 0; t < 8; ++t) {
        int idx = tid + t * 256;
        int r = idx >> 6, c4 = (idx & 63) * 4;
        float4 x = *(const float4*)(X + (size_t)(n0 + r) * KD + c4);
        ushort h0 = f2bf(x.x), h1 = f2bf(x.y), h2 = f2bf(x.z), h3 = f2bf(x.w);
        unsigned a = ((unsigned)h0) | ((unsigned)h1 << 16);
        unsigned b = ((unsigned)h2) | ((unsigned)h3 << 16);
        unsigned c = ((unsigned)f2bf(x.x - bf2f(h0))) | ((unsigned)f2bf(x.y - bf2f(h1)) << 16);
        unsigned d = ((unsigned)f2bf(x.z - bf2f(h2))) | ((unsigned)f2bf(x.w - bf2f(h3)) << 16);
        *(uint2*)&Xhi[r][c4] = make_uint2(a, b);
        *(uint2*)&Xlo[r][c4] = make_uint2(c, d);
    }
    __syncthreads();
#pragma unroll
    for (int ni = 0; ni < 2; ++ni) {
        v8s Ah[8], Al[8];
#pragma unroll
        for (int ks = 0; ks < 8; ++ks) {
            Ah[ks] = *(const v8s*)&Xhi[ni * 16 + lm][ks * 32 + lq * 8];
            Al[ks] = *(const v8s*)&Xlo[ni * 16 + lm][ks * 32 + lq * 8];
        }
        v4f acc[2] = {{0.f, 0.f, 0.f, 0.f}, {0.f, 0.f, 0.f, 0.f}};
#pragma unroll
        for (int ks = 0; ks < 8; ++ks)
#pragma unroll
            for (int hi = 0; hi < 2; ++hi) {
                acc[hi] = __builtin_amdgcn_mfma_f32_16x16x32_bf16(Ah[ks], Whi[hi][ks], acc[hi], 0, 0, 0);
                acc[hi] = __builtin_amdgcn_mfma_f32_16x16x32_bf16(Ah[ks], Wlo[hi][ks], acc[hi], 0, 0, 0);
                acc[hi] = __builtin_amdgcn_mfma_f32_16x16x32_bf16(Al[ks], Whi[hi][ks], acc[hi], 0, 0, 0);
            }
#pragma unroll
        for (int hi = 0; hi < 2; ++hi) {
            int h = hbase + hi * 16 + lm;
            int nb = n0 + ni * 16 + lq * 4;
            ushort b0 = f2bf(acc[hi][0]), b1 = f2bf(acc[hi][1]);
            ushort b2 = f2bf(acc[hi][2]), b3 = f2bf(acc[hi][3]);
            Zb[(size_t)(nb + 0) * HD + h] = b0;
            Zb[(size_t)(nb + 1) * HD + h] = b1;
            Zb[(size_t)(nb + 2) * HD + h] = b2;
            Zb[(size_t)(nb + 3) * HD + h] = b3;
            *(uint2*)&ZbT[(size_t)h * NR + nb] =
                make_uint2(((unsigned)b0) | ((unsigned)b1 << 16), ((unsigned)b2) | ((unsigned)b3 << 16));
        }
    }
}

// ---------------- K2: fused rowsum + V partials (no staging, no atomics) ----------------
// grid 1024 = 256 row-strips (32 rows) x 4 col-quarters (2048 cols); 16 iters x 128 cols.
// Wave w: S phase owns cols [w*32, w*32+32); V phase owns h [w*32, w*32+32).
__global__ __launch_bounds__(256) void k_sv(const ushort* __restrict__ Zb,
                                            const ushort* __restrict__ ZbT,
                                            float* __restrict__ rsP,
                                            float* __restrict__ Vp) {
    __shared__ ushort PT[2][32][136];  // bf16(relu(S)) tile [r][c-rel], double-buffered
    __shared__ float rsred[4][32];
    int tid = threadIdx.x, lane = tid & 63, wave = tid >> 6;
    int lm = lane & 15, lq = lane >> 4;
    int rb = blockIdx.x >> 2, q = blockIdx.x & 3;
    int row0 = rb * 32, cbase = q * 2048;
    // B-frags for S^T: the block's 32 Z-rows, straight from L2 (loaded once)
    v8s Bfr[2][4];
#pragma unroll
    for (int ri = 0; ri < 2; ++ri)
#pragma unroll
        for (int ks = 0; ks < 4; ++ks)
            Bfr[ri][ks] = *(const v8s*)(Zb + (size_t)(row0 + ri * 16 + lm) * HD + ks * 32 + lq * 8);
    float rs[2] = {0.f, 0.f};
    v4f V[2][2];  // [ri over rows][hi over h]
#pragma unroll
    for (int ri = 0; ri < 2; ++ri)
#pragma unroll
        for (int hi = 0; hi < 2; ++hi) V[ri][hi] = (v4f){0.f, 0.f, 0.f, 0.f};

    const ushort* afp = Zb + (size_t)(cbase + wave * 32 + lm) * HD + lq * 8;
    const ushort* bzp = ZbT + (size_t)(wave * 32 + lm) * NR + cbase + lq * 8;

    for (int it = 0; it < 16; ++it) {
        // V-phase B-frags (Z^T slice), issued early so L2 latency hides under S phase
        v8s Bz[2][4];
#pragma unroll
        for (int hi = 0; hi < 2; ++hi)
#pragma unroll
            for (int ks = 0; ks < 4; ++ks)
                Bz[hi][ks] = *(const v8s*)(bzp + (size_t)hi * 16 * NR + ks * 32);
        // S phase: S^T = (Z cols as A) x (Z rows as B); D: r=lm, c=lq*4+reg
#pragma unroll
        for (int ci = 0; ci < 2; ++ci) {
            v8s Af[4];
#pragma unroll
            for (int ks = 0; ks < 4; ++ks)
                Af[ks] = *(const v8s*)(afp + (size_t)(ci * 16) * HD + ks * 32);
            v4f a0 = {0.f, 0.f, 0.f, 0.f}, a1 = {0.f, 0.f, 0.f, 0.f};
#pragma unroll
            for (int ks = 0; ks < 4; ++ks) {
                a0 = __builtin_amdgcn_mfma_f32_16x16x32_bf16(Af[ks], Bfr[0][ks], a0, 0, 0, 0);
                a1 = __builtin_amdgcn_mfma_f32_16x16x32_bf16(Af[ks], Bfr[1][ks], a1, 0, 0, 0);
            }
            int cc = wave * 32 + ci * 16 + lq * 4;
            {
                float f0 = fmaxf(a0[0], 0.f), f1 = fmaxf(a0[1], 0.f);
                float f2 = fmaxf(a0[2], 0.f), f3 = fmaxf(a0[3], 0.f);
                rs[0] += f0 + f1 + f2 + f3;
                *(uint2*)&PT[it & 1][lm][cc] = make_uint2(cvtpk(f0, f1), cvtpk(f2, f3));
            }
            {
                float f0 = fmaxf(a1[0], 0.f), f1 = fmaxf(a1[1], 0.f);
                float f2 = fmaxf(a1[2], 0.f), f3 = fmaxf(a1[3], 0.f);
                rs[1] += f0 + f1 + f2 + f3;
                *(uint2*)&PT[it & 1][16 + lm][cc] = make_uint2(cvtpk(f0, f1), cvtpk(f2, f3));
            }
        }
        __syncthreads();  // PT[it&1] complete; prev iter's PT[it&1^1] readers already done
        // V phase: V[r][h] += P[r][c] * Z[c][h]; A = PT frag, B = Bz (regs)
#pragma unroll
        for (int ks = 0; ks < 4; ++ks) {
            v8s P0 = *(const v8s*)&PT[it & 1][lm][ks * 32 + lq * 8];
            v8s P1 = *(const v8s*)&PT[it & 1][16 + lm][ks * 32 + lq * 8];
#pragma unroll
            for (int hi = 0; hi < 2; ++hi) {
                V[0][hi] = __builtin_amdgcn_mfma_f32_16x16x32_bf16(P0, Bz[hi][ks], V[0][hi], 0, 0, 0);
                V[1][hi] = __builtin_amdgcn_mfma_f32_16x16x32_bf16(P1, Bz[hi][ks], V[1][hi], 0, 0, 0);
            }
        }
        afp += (size_t)128 * HD;
        bzp += 128;
    }
    // rowsum quarter-partial: reduce over lq (shfl) then across waves (LDS), plain store
#pragma unroll
    for (int ri = 0; ri < 2; ++ri) {
        float v = rs[ri];
        v += __shfl_xor(v, 16, 64);
        v += __shfl_xor(v, 32, 64);
        if (lq == 0) rsred[wave][ri * 16 + lm] = v;
    }
    __syncthreads();
    if (tid < 32)
        rsP[(size_t)q * NR + row0 + tid] =
            rsred[0][tid] + rsred[1][tid] + rsred[2][tid] + rsred[3][tid];
    // V quarter-partial: each (row,h) owned by exactly one block/wave -> plain stores
    float* vbase = Vp + (size_t)q * NR * HD + (size_t)row0 * HD + wave * 32;
#pragma unroll
    for (int ri = 0; ri < 2; ++ri)
#pragma unroll
        for (int hi = 0; hi < 2; ++hi)
#pragma unroll
            for (int j = 0; j < 4; ++j)
                vbase[(size_t)(ri * 16 + lq * 4 + j) * HD + hi * 16 + lm] = V[ri][hi][j];
}

// ---------------- K3: out = (sum of V partials) * rsinv ----------------
__global__ __launch_bounds__(256) void k_out(const float* __restrict__ Vp,
                                             const float* __restrict__ rsP,
                                             float* __restrict__ outp) {
    int idx = blockIdx.x * 256 + threadIdx.x;  // float4 index, 262144 total
    int r = idx >> 5, h4 = (idx & 31) * 4;
    float rsv = 1.0f / (rsP[r] + rsP[NR + r] + rsP[2 * NR + r] + rsP[3 * NR + r] + 1e-6f);
    size_t o = (size_t)r * HD + h4;
    float4 v0 = *(const float4*)(Vp + o);
    float4 v1 = *(const float4*)(Vp + (size_t)NR * HD + o);
    float4 v2 = *(const float4*)(Vp + 2 * (size_t)NR * HD + o);
    float4 v3 = *(const float4*)(Vp + 3 * (size_t)NR * HD + o);
    float4 s = make_float4((v0.x + v1.x + v2.x + v3.x) * rsv, (v0.y + v1.y + v2.y + v3.y) * rsv,
                           (v0.z + v1.z + v2.z + v3.z) * rsv, (v0.w + v1.w + v2.w + v3.w) * rsv);
    *(float4*)(outp + o) = s;
}

// ---------------- K4: A writer — zero LDS, zero barriers ----------------
// grid 512 = 128 rb (64 rows) x 4 cs (2048 cols); 32 iters x 64 cols.
__global__ __launch_bounds__(256) void k_a(const ushort* __restrict__ Zb,
                                           const float* __restrict__ rsP,
                                           float* __restrict__ Ap) {
    int tid = threadIdx.x, lane = tid & 63, wave = tid >> 6;
    int lm = lane & 15, lq = lane >> 4;
    int rb = blockIdx.x >> 2, cs = blockIdx.x & 3;
    int row0 = rb * 64, colb = cs * 2048;
    int wr2 = wave >> 1, wc2 = wave & 1;
    v8s Bfr[2][4];
#pragma unroll
    for (int ri = 0; ri < 2; ++ri)
#pragma unroll
        for (int ks = 0; ks < 4; ++ks)
            Bfr[ri][ks] =
                *(const v8s*)(Zb + (size_t)(row0 + wr2 * 32 + ri * 16 + lm) * HD + ks * 32 + lq * 8);
    float rsv[2];
#pragma unroll
    for (int ri = 0; ri < 2; ++ri) {
        int r = row0 + wr2 * 32 + ri * 16 + lm;
        rsv[ri] = 1.0f / (rsP[r] + rsP[NR + r] + rsP[2 * NR + r] + rsP[3 * NR + r] + 1e-6f);
    }
    const ushort* afp = Zb + (size_t)(colb + wc2 * 32 + lm) * HD + lq * 8;
    float* ap0 = Ap + (size_t)(row0 + wr2 * 32 + lm) * NR + colb + wc2 * 32 + lq * 4;
    float* ap1 = ap0 + (size_t)16 * NR;
    for (int it = 0; it < 32; ++it) {
#pragma unroll
        for (int ci = 0; ci < 2; ++ci) {
            v8s Af[4];
#pragma unroll
            for (int ks = 0; ks < 4; ++ks)
                Af[ks] = *(const v8s*)(afp + (size_t)(ci * 16) * HD + ks * 32);
            v4f S0 = {0.f, 0.f, 0.f, 0.f}, S1 = {0.f, 0.f, 0.f, 0.f};
#pragma unroll
            for (int ks = 0; ks < 4; ++ks) {
                S0 = __builtin_amdgcn_mfma_f32_16x16x32_bf16(Af[ks], Bfr[0][ks], S0, 0, 0, 0);
                S1 = __builtin_amdgcn_mfma_f32_16x16x32_bf16(Af[ks], Bfr[1][ks], S1, 0, 0, 0);
            }
            v4f av;
            av[0] = fmaxf(S0[0], 0.f) * rsv[0]; av[1] = fmaxf(S0[1], 0.f) * rsv[0];
            av[2] = fmaxf(S0[2], 0.f) * rsv[0]; av[3] = fmaxf(S0[3], 0.f) * rsv[0];
            __builtin_nontemporal_store(av, (v4f*)(ap0 + ci * 16));
            av[0] = fmaxf(S1[0], 0.f) * rsv[1]; av[1] = fmaxf(S1[1], 0.f) * rsv[1];
            av[2] = fmaxf(S1[2], 0.f) * rsv[1]; av[3] = fmaxf(S1[3], 0.f) * rsv[1];
            __builtin_nontemporal_store(av, (v4f*)(ap1 + ci * 16));
        }
        afp += (size_t)64 * HD;
        ap0 += 64;
        ap1 += 64;
    }
}

extern "C" void kernel_launch(void* const* d_in, const int* in_sizes, int n_in,
                              void* d_out, int out_size, void* d_ws, size_t ws_size,
                              hipStream_t stream) {
    (void)in_sizes; (void)n_in; (void)out_size; (void)ws_size;
    const float* X = (const float*)d_in[0];
    const float* W = (const float*)d_in[1];
    float* outp = (float*)d_out;
    float* Ap = outp + (size_t)NR * HD;  // A follows out in d_out
    // V partials live in the last 16 MB of the A buffer; k_out consumes them BEFORE k_a
    // overwrites the whole of A. No extra workspace, no memsets (all outputs fully written).
    float* Vp = Ap + ((size_t)NR * NR - 4 * (size_t)NR * HD);
    char* ws = (char*)d_ws;
    ushort* Zb = (ushort*)ws;                             // 2 MB
    ushort* ZbT = (ushort*)(ws + (size_t)NR * HD * 2);    // 2 MB
    float* rsP = (float*)(ws + (size_t)NR * HD * 4);      // 4 x 32 KB quarter partials

    k_z<<<dim3(NR / 32), dim3(256), 0, stream>>>(X, W, Zb, ZbT);
    k_sv<<<dim3(1024), dim3(256), 0, stream>>>(Zb, ZbT, rsP, Vp);
    k_out<<<dim3(1024), dim3(256), 0, stream>>>(Vp, rsP, outp);
    k_a<<<dim3(512), dim3(256), 0, stream>>>(Zb, rsP, Ap);
}

// Round 3
// 431.177 us; speedup vs baseline: 1.1220x; 1.1220x over previous
//
#include <hip/hip_runtime.h>

// AdaptiveGraph on MI355X — v3: round-0 structure, occupancy-fixed.
// K1 k_z  : Z = X W^T via bf16 MFMA hi/lo split; writes Zb [n][h] + ZbT [h][n]. (proven)
// K2 k_sv : 64-row strip x 1024-col eighth, 16 iters x 64 cols. Per iter:
//           stage ZC (coalesced) + ZCT (coalesced) -> S^T MFMA (B-frags: one-time global)
//           -> relu -> rowsum atomics + PT (bf16) -> U += PT @ ZCT (second MFMA).
//           LDS 44 KB -> 3 blocks/CU. V unnormalized -> Vacc atomics (round-1-proven layout).
// K3 k_out: out = Vacc * rsinv. (proven)
// K4 k_a  : round-1 A-writer minus ZR staging: stage ZC only (17 KB LDS), S^T MFMA,
//           relu*rsinv, nontemporal float4 stores. (proven mechanics)

#define NR 8192
#define KD 256
#define HD 128

typedef short v8s __attribute__((ext_vector_type(8)));
typedef float v4f __attribute__((ext_vector_type(4)));

static __device__ __forceinline__ ushort f2bf(float f) {
    union { float f; unsigned u; } c; c.f = f;
    unsigned u = c.u;
    u += 0x7fffu + ((u >> 16) & 1u);  // RNE; inputs finite
    return (ushort)(u >> 16);
}
static __device__ __forceinline__ float bf2f(ushort b) {
    union { unsigned u; float f; } c; c.u = ((unsigned)b) << 16; return c.f;
}
static __device__ __forceinline__ unsigned pk2(float a, float b) {
    union { float f; unsigned u; } x, y; x.f = a; y.f = b;
    unsigned ua = x.u + 0x7fffu + ((x.u >> 16) & 1u);
    unsigned ub = y.u + 0x7fffu + ((y.u >> 16) & 1u);
    return (ua >> 16) | (ub & 0xffff0000u);
}

// ---------------- K1: Z = X @ W^T (MFMA, hi/lo bf16 split) ----------------
__global__ __launch_bounds__(256) void k_z(const float* __restrict__ X,
                                           const float* __restrict__ W,
                                           ushort* __restrict__ Zb,
                                           ushort* __restrict__ ZbT) {
    __shared__ ushort Xhi[32][264];
    __shared__ ushort Xlo[32][264];
    int tid = threadIdx.x, lane = tid & 63, wave = tid >> 6;
    int lm = lane & 15, lq = lane >> 4;
    int n0 = blockIdx.x * 32;
    int hbase = wave * 32;
    v8s Whi[2][8], Wlo[2][8];
#pragma unroll
    for (int hi = 0; hi < 2; ++hi) {
        const float* wp = W + (hbase + hi * 16 + lm) * KD + lq * 8;
#pragma unroll
        for (int ks = 0; ks < 8; ++ks) {
            float4 w0 = *(const float4*)(wp + ks * 32);
            float4 w1 = *(const float4*)(wp + ks * 32 + 4);
            float wv[8] = {w0.x, w0.y, w0.z, w0.w, w1.x, w1.y, w1.z, w1.w};
#pragma unroll
            for (int j = 0; j < 8; ++j) {
                ushort h = f2bf(wv[j]);
                Whi[hi][ks][j] = (short)h;
                Wlo[hi][ks][j] = (short)f2bf(wv[j] - bf2f(h));
            }
        }
    }
#pragma unroll
    for (int t = 0; t < 8; ++t) {
        int idx = tid + t * 256;
        int r = idx >> 6, c4 = (idx & 63) * 4;
        float4 x = *(const float4*)(X + (size_t)(n0 + r) * KD + c4);
        ushort h0 = f2bf(x.x), h1 = f2bf(x.y), h2 = f2bf(x.z), h3 = f2bf(x.w);
        unsigned a = ((unsigned)h0) | ((unsigned)h1 << 16);
        unsigned b = ((unsigned)h2) | ((unsigned)h3 << 16);
        unsigned c = ((unsigned)f2bf(x.x - bf2f(h0))) | ((unsigned)f2bf(x.y - bf2f(h1)) << 16);
        unsigned d = ((unsigned)f2bf(x.z - bf2f(h2))) | ((unsigned)f2bf(x.w - bf2f(h3)) << 16);
        *(uint2*)&Xhi[r][c4] = make_uint2(a, b);
        *(uint2*)&Xlo[r][c4] = make_uint2(c, d);
    }
    __syncthreads();
#pragma unroll
    for (int ni = 0; ni < 2; ++ni) {
        v8s Ah[8], Al[8];
#pragma unroll
        for (int ks = 0; ks < 8; ++ks) {
            Ah[ks] = *(const v8s*)&Xhi[ni * 16 + lm][ks * 32 + lq * 8];
            Al[ks] = *(const v8s*)&Xlo[ni * 16 + lm][ks * 32 + lq * 8];
        }
        v4f acc[2] = {{0.f, 0.f, 0.f, 0.f}, {0.f, 0.f, 0.f, 0.f}};
#pragma unroll
        for (int ks = 0; ks < 8; ++ks)
#pragma unroll
            for (int hi = 0; hi < 2; ++hi) {
                acc[hi] = __builtin_amdgcn_mfma_f32_16x16x32_bf16(Ah[ks], Whi[hi][ks], acc[hi], 0, 0, 0);
                acc[hi] = __builtin_amdgcn_mfma_f32_16x16x32_bf16(Ah[ks], Wlo[hi][ks], acc[hi], 0, 0, 0);
                acc[hi] = __builtin_amdgcn_mfma_f32_16x16x32_bf16(Al[ks], Whi[hi][ks], acc[hi], 0, 0, 0);
            }
#pragma unroll
        for (int hi = 0; hi < 2; ++hi) {
            int h = hbase + hi * 16 + lm;
            int nb = n0 + ni * 16 + lq * 4;
            ushort b0 = f2bf(acc[hi][0]), b1 = f2bf(acc[hi][1]);
            ushort b2 = f2bf(acc[hi][2]), b3 = f2bf(acc[hi][3]);
            Zb[(size_t)(nb + 0) * HD + h] = b0;
            Zb[(size_t)(nb + 1) * HD + h] = b1;
            Zb[(size_t)(nb + 2) * HD + h] = b2;
            Zb[(size_t)(nb + 3) * HD + h] = b3;
            *(uint2*)&ZbT[(size_t)h * NR + nb] =
                make_uint2(((unsigned)b0) | ((unsigned)b1 << 16), ((unsigned)b2) | ((unsigned)b3 << 16));
        }
    }
}

// ---------------- K2: fused rowsum + V (un-normalized out) ----------------
// grid 1024 = 128 rb (64 rows) x 8 cs (1024 cols); 16 iters x 64 cols. 44 KB LDS.
__global__ __launch_bounds__(256) void k_sv(const ushort* __restrict__ Zb,
                                            const ushort* __restrict__ ZbT,
                                            float* __restrict__ rowsum,
                                            float* __restrict__ Vacc) {
    __shared__ ushort ZC[64][136];
    __shared__ ushort ZCT[128][72];  // Z tile [h][c-rel] for U B-operand
    __shared__ ushort PT[64][72];    // bf16(relu(S)) tile [r][c-rel]
    int tid = threadIdx.x, lane = tid & 63, wave = tid >> 6;
    int lm = lane & 15, lq = lane >> 4;
    int rb = blockIdx.x >> 3, cs = blockIdx.x & 7;
    int row0 = rb * 64, colb = cs * 1024;
    int wr2 = wave >> 1, wc2 = wave & 1;
    // one-time B-frags for S^T from global (scattered is fine: once per block)
    v8s Bfr[2][4];
#pragma unroll
    for (int ri = 0; ri < 2; ++ri)
#pragma unroll
        for (int ks = 0; ks < 4; ++ks)
            Bfr[ri][ks] =
                *(const v8s*)(Zb + (size_t)(row0 + wr2 * 32 + ri * 16 + lm) * HD + ks * 32 + lq * 8);
    float rs[2] = {0.f, 0.f};
    v4f U[2][4];
#pragma unroll
    for (int ri = 0; ri < 2; ++ri)
#pragma unroll
        for (int hi = 0; hi < 4; ++hi) U[ri][hi] = (v4f){0.f, 0.f, 0.f, 0.f};

    for (int it = 0; it < 16; ++it) {
        int c0 = colb + it * 64;
        __syncthreads();  // prev iter's reads of ZC/ZCT/PT done
#pragma unroll
        for (int t = 0; t < 4; ++t) {
            int idx = tid + t * 256;
            int r = idx >> 4, c8 = (idx & 15) * 8;
            *(uint4*)&ZC[r][c8] = *(const uint4*)(Zb + (size_t)(c0 + r) * HD + c8);
        }
#pragma unroll
        for (int t = 0; t < 4; ++t) {
            int idx = tid + t * 256;
            int hh = idx >> 3, cc8 = (idx & 7) * 8;
            *(uint4*)&ZCT[hh][cc8] = *(const uint4*)(ZbT + (size_t)hh * NR + c0 + cc8);
        }
        __syncthreads();
        // S^T = (ZC as A) x (Zrows as B): D[m=c][n=r] -> lane: r=lm, c=lq*4+reg
#pragma unroll
        for (int ci = 0; ci < 2; ++ci) {
            v8s Af[4];
#pragma unroll
            for (int ks = 0; ks < 4; ++ks)
                Af[ks] = *(const v8s*)&ZC[wc2 * 32 + ci * 16 + lm][ks * 32 + lq * 8];
            v4f S0 = {0.f, 0.f, 0.f, 0.f}, S1 = {0.f, 0.f, 0.f, 0.f};
#pragma unroll
            for (int ks = 0; ks < 4; ++ks) {
                S0 = __builtin_amdgcn_mfma_f32_16x16x32_bf16(Af[ks], Bfr[0][ks], S0, 0, 0, 0);
                S1 = __builtin_amdgcn_mfma_f32_16x16x32_bf16(Af[ks], Bfr[1][ks], S1, 0, 0, 0);
            }
            int cb = wc2 * 32 + ci * 16 + lq * 4;
            {
                float f0 = fmaxf(S0[0], 0.f), f1 = fmaxf(S0[1], 0.f);
                float f2 = fmaxf(S0[2], 0.f), f3 = fmaxf(S0[3], 0.f);
                rs[0] += f0 + f1 + f2 + f3;
                *(uint2*)&PT[wr2 * 32 + lm][cb] = make_uint2(pk2(f0, f1), pk2(f2, f3));
            }
            {
                float f0 = fmaxf(S1[0], 0.f), f1 = fmaxf(S1[1], 0.f);
                float f2 = fmaxf(S1[2], 0.f), f3 = fmaxf(S1[3], 0.f);
                rs[1] += f0 + f1 + f2 + f3;
                *(uint2*)&PT[wr2 * 32 + 16 + lm][cb] = make_uint2(pk2(f0, f1), pk2(f2, f3));
            }
        }
        __syncthreads();  // PT visible
        // U[r][h] += P[r][c] * Z[c][h]; A = PT frag, B = ZCT frag
#pragma unroll
        for (int ks = 0; ks < 2; ++ks) {
            v8s P0 = *(const v8s*)&PT[wr2 * 32 + lm][ks * 32 + lq * 8];
            v8s P1 = *(const v8s*)&PT[wr2 * 32 + 16 + lm][ks * 32 + lq * 8];
#pragma unroll
            for (int hi = 0; hi < 4; ++hi) {
                v8s Bz = *(const v8s*)&ZCT[wc2 * 64 + hi * 16 + lm][ks * 32 + lq * 8];
                U[0][hi] = __builtin_amdgcn_mfma_f32_16x16x32_bf16(P0, Bz, U[0][hi], 0, 0, 0);
                U[1][hi] = __builtin_amdgcn_mfma_f32_16x16x32_bf16(P1, Bz, U[1][hi], 0, 0, 0);
            }
        }
    }
    // rowsum partials: reduce across lq groups, one atomic per row per wave
#pragma unroll
    for (int ri = 0; ri < 2; ++ri) {
        float v = rs[ri];
        v += __shfl_xor(v, 16, 64);
        v += __shfl_xor(v, 32, 64);
        if (lq == 0) atomicAdd(&rowsum[row0 + wr2 * 32 + ri * 16 + lm], v);
    }
    // V partials: D layout -> r = row0+wr2*32+ri*16+lq*4+j, h = wc2*64+hi*16+lm
#pragma unroll
    for (int ri = 0; ri < 2; ++ri)
#pragma unroll
        for (int hi = 0; hi < 4; ++hi)
#pragma unroll
            for (int j = 0; j < 4; ++j)
                atomicAdd(&Vacc[(size_t)(row0 + wr2 * 32 + ri * 16 + lq * 4 + j) * HD +
                                wc2 * 64 + hi * 16 + lm],
                          U[ri][hi][j]);
}

// ---------------- K3: out = Vacc * rsinv ----------------
__global__ __launch_bounds__(256) void k_out(const float* __restrict__ Vacc,
                                             const float* __restrict__ rowsum,
                                             float* __restrict__ outp) {
    int idx = blockIdx.x * 256 + threadIdx.x;  // float4 index, 262144 total
    int r = idx >> 5, h4 = (idx & 31) * 4;
    float rsv = 1.0f / (rowsum[r] + 1e-6f);
    float4 v = *(const float4*)(Vacc + (size_t)r * HD + h4);
    float4 o = make_float4(v.x * rsv, v.y * rsv, v.z * rsv, v.w * rsv);
    *(float4*)(outp + (size_t)r * HD + h4) = o;
}

// ---------------- K4: A writer — ZC staging only (17 KB LDS) ----------------
// grid 1024 = 128 rb (64 rows) x 8 cs (1024 cols); 16 iters x 64 cols.
__global__ __launch_bounds__(256) void k_a(const ushort* __restrict__ Zb,
                                           const float* __restrict__ rowsum,
                                           float* __restrict__ Ap) {
    __shared__ ushort ZC[64][136];
    int tid = threadIdx.x, lane = tid & 63, wave = tid >> 6;
    int lm = lane & 15, lq = lane >> 4;
    int rb = blockIdx.x >> 3, cs = blockIdx.x & 7;
    int row0 = rb * 64, colb = cs * 1024;
    int wr2 = wave >> 1, wc2 = wave & 1;
    v8s Bfr[2][4];  // one-time, from global
#pragma unroll
    for (int ri = 0; ri < 2; ++ri)
#pragma unroll
        for (int ks = 0; ks < 4; ++ks)
            Bfr[ri][ks] =
                *(const v8s*)(Zb + (size_t)(row0 + wr2 * 32 + ri * 16 + lm) * HD + ks * 32 + lq * 8);
    float rsv[2];
#pragma unroll
    for (int ri = 0; ri < 2; ++ri)
        rsv[ri] = 1.0f / (rowsum[row0 + wr2 * 32 + ri * 16 + lm] + 1e-6f);
    float* ap0 = Ap + (size_t)(row0 + wr2 * 32 + lm) * NR + colb + wc2 * 32 + lq * 4;
    float* ap1 = ap0 + (size_t)16 * NR;

    for (int it = 0; it < 16; ++it) {
        int c0 = colb + it * 64;
        __syncthreads();
#pragma unroll
        for (int t = 0; t < 4; ++t) {
            int idx = tid + t * 256;
            int r = idx >> 4, c8 = (idx & 15) * 8;
            *(uint4*)&ZC[r][c8] = *(const uint4*)(Zb + (size_t)(c0 + r) * HD + c8);
        }
        __syncthreads();
#pragma unroll
        for (int ci = 0; ci < 2; ++ci) {
            v8s Af[4];
#pragma unroll
            for (int ks = 0; ks < 4; ++ks)
                Af[ks] = *(const v8s*)&ZC[wc2 * 32 + ci * 16 + lm][ks * 32 + lq * 8];
            v4f S0 = {0.f, 0.f, 0.f, 0.f}, S1 = {0.f, 0.f, 0.f, 0.f};
#pragma unroll
            for (int ks = 0; ks < 4; ++ks) {
                S0 = __builtin_amdgcn_mfma_f32_16x16x32_bf16(Af[ks], Bfr[0][ks], S0, 0, 0, 0);
                S1 = __builtin_amdgcn_mfma_f32_16x16x32_bf16(Af[ks], Bfr[1][ks], S1, 0, 0, 0);
            }
            v4f av;
            av[0] = fmaxf(S0[0], 0.f) * rsv[0]; av[1] = fmaxf(S0[1], 0.f) * rsv[0];
            av[2] = fmaxf(S0[2], 0.f) * rsv[0]; av[3] = fmaxf(S0[3], 0.f) * rsv[0];
            __builtin_nontemporal_store(av, (v4f*)(ap0 + ci * 16));
            av[0] = fmaxf(S1[0], 0.f) * rsv[1]; av[1] = fmaxf(S1[1], 0.f) * rsv[1];
            av[2] = fmaxf(S1[2], 0.f) * rsv[1]; av[3] = fmaxf(S1[3], 0.f) * rsv[1];
            __builtin_nontemporal_store(av, (v4f*)(ap1 + ci * 16));
        }
        ap0 += 64;
        ap1 += 64;
    }
}

extern "C" void kernel_launch(void* const* d_in, const int* in_sizes, int n_in,
                              void* d_out, int out_size, void* d_ws, size_t ws_size,
                              hipStream_t stream) {
    (void)in_sizes; (void)n_in; (void)out_size; (void)ws_size;
    const float* X = (const float*)d_in[0];
    const float* W = (const float*)d_in[1];
    float* outp = (float*)d_out;
    float* Ap = outp + (size_t)NR * HD;  // A follows out in d_out
    char* ws = (char*)d_ws;
    ushort* Zb = (ushort*)ws;                                   // 2 MB
    ushort* ZbT = (ushort*)(ws + (size_t)NR * HD * 2);          // 2 MB
    float* rowsum = (float*)(ws + (size_t)NR * HD * 4);         // 32 KB
    float* Vacc = (float*)(ws + (size_t)NR * HD * 4 + NR * 4);  // 4 MB (round-1-proven layout)

    (void)hipMemsetAsync(rowsum, 0, NR * sizeof(float), stream);
    (void)hipMemsetAsync(Vacc, 0, (size_t)NR * HD * sizeof(float), stream);
    k_z<<<dim3(NR / 32), dim3(256), 0, stream>>>(X, W, Zb, ZbT);
    k_sv<<<dim3(1024), dim3(256), 0, stream>>>(Zb, ZbT, rowsum, Vacc);
    k_out<<<dim3(1024), dim3(256), 0, stream>>>(Vacc, rowsum, outp);
    k_a<<<dim3(1024), dim3(256), 0, stream>>>(Zb, rowsum, Ap);
}

// Round 4
// 411.570 us; speedup vs baseline: 1.1754x; 1.0476x over previous
//
#include <hip/hip_runtime.h>

// AdaptiveGraph on MI355X.
// Round-0 proven structure (367 us), ONE change: ZR LDS staging removed from
// k_rowsum/k_main — B-fragments (Bfr) are loaded once per block directly from
// global (L2-resident Zb). LDS: k_rowsum 69.6->34.8 KB (2->4 blocks/CU),
// k_main 62.5->45.1 KB (2->3 blocks/CU). Everything else byte-identical.
// K1: Z = X W^T via bf16 MFMA with hi/lo split (fp32-accurate); writes Zb [n][h] + ZbT [h][n].
// K2: rowsum[r] = sum_c relu(Z_r . Z_c). 128x128 block tiles, 64x64/wave, reg-cached Bfr frags.
// K3: recompute S^T tiles (c-major C-layout -> float4 A-stores + b64 P-stores),
//     A = relu(S)*rsinv (fp32, nontemporal), out += P @ Z via second MFMA, atomicAdd.

#define NR 8192
#define KD 256
#define HD 128

typedef short v8s __attribute__((ext_vector_type(8)));
typedef float v4f __attribute__((ext_vector_type(4)));

static __device__ __forceinline__ ushort f2bf(float f) {
    union { float f; unsigned u; } c; c.f = f;
    unsigned u = c.u;
    u += 0x7fffu + ((u >> 16) & 1u);  // RNE; inputs finite
    return (ushort)(u >> 16);
}
static __device__ __forceinline__ float bf2f(ushort b) {
    union { unsigned u; float f; } c; c.u = ((unsigned)b) << 16; return c.f;
}
static __device__ __forceinline__ unsigned pk2(float a, float b) {
    union { float f; unsigned u; } x, y; x.f = a; y.f = b;
    unsigned ua = x.u + 0x7fffu + ((x.u >> 16) & 1u);
    unsigned ub = y.u + 0x7fffu + ((y.u >> 16) & 1u);
    return (ua >> 16) | (ub & 0xffff0000u);
}

// ---------------- K1: Z = X @ W^T (MFMA, hi/lo bf16 split) ----------------
// grid 256 blocks x 256 thr; block = 32 rows of X; wave owns 32 h-columns.
__global__ __launch_bounds__(256) void k_z(const float* __restrict__ X,
                                           const float* __restrict__ W,
                                           ushort* __restrict__ Zb,
                                           ushort* __restrict__ ZbT) {
    __shared__ ushort Xhi[32][264];  // +8 pad: stride 132 dwords == 4 mod 32 -> 2-way (free)
    __shared__ ushort Xlo[32][264];
    int tid = threadIdx.x, lane = tid & 63, wave = tid >> 6;
    int lm = lane & 15, lq = lane >> 4;
    int n0 = blockIdx.x * 32;
    int hbase = wave * 32;
    // W fragments cached in regs (hi/lo), reused for both n-tiles
    v8s Whi[2][8], Wlo[2][8];
#pragma unroll
    for (int hi = 0; hi < 2; ++hi) {
        const float* wp = W + (hbase + hi * 16 + lm) * KD + lq * 8;
#pragma unroll
        for (int ks = 0; ks < 8; ++ks) {
            float4 w0 = *(const float4*)(wp + ks * 32);
            float4 w1 = *(const float4*)(wp + ks * 32 + 4);
            float wv[8] = {w0.x, w0.y, w0.z, w0.w, w1.x, w1.y, w1.z, w1.w};
#pragma unroll
            for (int j = 0; j < 8; ++j) {
                ushort h = f2bf(wv[j]);
                Whi[hi][ks][j] = (short)h;
                Wlo[hi][ks][j] = (short)f2bf(wv[j] - bf2f(h));
            }
        }
    }
    // stage X tile 32x256 as hi/lo bf16
#pragma unroll
    for (int t = 0; t < 8; ++t) {
        int idx = tid + t * 256;
        int r = idx >> 6, c4 = (idx & 63) * 4;
        float4 x = *(const float4*)(X + (size_t)(n0 + r) * KD + c4);
        ushort h0 = f2bf(x.x), h1 = f2bf(x.y), h2 = f2bf(x.z), h3 = f2bf(x.w);
        unsigned a = ((unsigned)h0) | ((unsigned)h1 << 16);
        unsigned b = ((unsigned)h2) | ((unsigned)h3 << 16);
        unsigned c = ((unsigned)f2bf(x.x - bf2f(h0))) | ((unsigned)f2bf(x.y - bf2f(h1)) << 16);
        unsigned d = ((unsigned)f2bf(x.z - bf2f(h2))) | ((unsigned)f2bf(x.w - bf2f(h3)) << 16);
        *(uint2*)&Xhi[r][c4] = make_uint2(a, b);
        *(uint2*)&Xlo[r][c4] = make_uint2(c, d);
    }
    __syncthreads();
#pragma unroll
    for (int ni = 0; ni < 2; ++ni) {
        v8s Ah[8], Al[8];
#pragma unroll
        for (int ks = 0; ks < 8; ++ks) {
            Ah[ks] = *(const v8s*)&Xhi[ni * 16 + lm][ks * 32 + lq * 8];
            Al[ks] = *(const v8s*)&Xlo[ni * 16 + lm][ks * 32 + lq * 8];
        }
        v4f acc[2] = {{0.f, 0.f, 0.f, 0.f}, {0.f, 0.f, 0.f, 0.f}};
#pragma unroll
        for (int ks = 0; ks < 8; ++ks)
#pragma unroll
            for (int hi = 0; hi < 2; ++hi) {
                acc[hi] = __builtin_amdgcn_mfma_f32_16x16x32_bf16(Ah[ks], Whi[hi][ks], acc[hi], 0, 0, 0);
                acc[hi] = __builtin_amdgcn_mfma_f32_16x16x32_bf16(Ah[ks], Wlo[hi][ks], acc[hi], 0, 0, 0);
                acc[hi] = __builtin_amdgcn_mfma_f32_16x16x32_bf16(Al[ks], Whi[hi][ks], acc[hi], 0, 0, 0);
            }
#pragma unroll
        for (int hi = 0; hi < 2; ++hi) {
            int h = hbase + hi * 16 + lm;   // D: col=lm -> h, row=lq*4+j -> n
            int nb = n0 + ni * 16 + lq * 4;
            ushort b0 = f2bf(acc[hi][0]), b1 = f2bf(acc[hi][1]);
            ushort b2 = f2bf(acc[hi][2]), b3 = f2bf(acc[hi][3]);
            Zb[(size_t)(nb + 0) * HD + h] = b0;
            Zb[(size_t)(nb + 1) * HD + h] = b1;
            Zb[(size_t)(nb + 2) * HD + h] = b2;
            Zb[(size_t)(nb + 3) * HD + h] = b3;
            *(uint2*)&ZbT[(size_t)h * NR + nb] =
                make_uint2(((unsigned)b0) | ((unsigned)b1 << 16), ((unsigned)b2) | ((unsigned)b3 << 16));
        }
    }
}

// ---------------- K2: rowsum ----------------
// grid 512 = 64 rb x 8 cs; block tile 128r x (8 iters x 128c); wave = 64r x 64c.
// LDS: ZC only (34.8 KB) -> 4 blocks/CU. Bfr loaded once from global.
__global__ __launch_bounds__(256) void k_rowsum(const ushort* __restrict__ Zb,
                                                float* __restrict__ rowsum) {
    __shared__ ushort ZC[128][136];
    int tid = threadIdx.x, lane = tid & 63, wave = tid >> 6;
    int lm = lane & 15, lq = lane >> 4;
    int rb = blockIdx.x >> 3, cs = blockIdx.x & 7;
    int row0 = rb * 128, cstart = cs * 1024;
    int wr2 = wave >> 1, wc2 = wave & 1;
    v8s Bfr[4][4];  // reg-cached row frags (B-operand for S^T), one-time global load
#pragma unroll
    for (int ri = 0; ri < 4; ++ri)
#pragma unroll
        for (int ks = 0; ks < 4; ++ks)
            Bfr[ri][ks] =
                *(const v8s*)(Zb + (size_t)(row0 + wr2 * 64 + ri * 16 + lm) * HD + ks * 32 + lq * 8);
    float rs[4] = {0.f, 0.f, 0.f, 0.f};
    for (int it = 0; it < 8; ++it) {
        int c0 = cstart + it * 128;
        __syncthreads();
#pragma unroll
        for (int t = 0; t < 8; ++t) {
            int idx = tid + t * 256;
            int r = idx >> 4, c8 = (idx & 15) * 8;
            *(uint4*)&ZC[r][c8] = *(const uint4*)(Zb + (size_t)(c0 + r) * HD + c8);
        }
        __syncthreads();
#pragma unroll
        for (int ci = 0; ci < 4; ++ci) {
            v8s Af[4];
#pragma unroll
            for (int ks = 0; ks < 4; ++ks)
                Af[ks] = *(const v8s*)&ZC[wc2 * 64 + ci * 16 + lm][ks * 32 + lq * 8];
            v4f acc[4] = {{0.f,0.f,0.f,0.f},{0.f,0.f,0.f,0.f},{0.f,0.f,0.f,0.f},{0.f,0.f,0.f,0.f}};
#pragma unroll
            for (int ks = 0; ks < 4; ++ks)
#pragma unroll
                for (int ri = 0; ri < 4; ++ri)
                    acc[ri] = __builtin_amdgcn_mfma_f32_16x16x32_bf16(Af[ks], Bfr[ri][ks], acc[ri], 0, 0, 0);
#pragma unroll
            for (int ri = 0; ri < 4; ++ri)
                rs[ri] += fmaxf(acc[ri][0], 0.f) + fmaxf(acc[ri][1], 0.f) +
                          fmaxf(acc[ri][2], 0.f) + fmaxf(acc[ri][3], 0.f);
        }
    }
#pragma unroll
    for (int ri = 0; ri < 4; ++ri) {
        float v = rs[ri];
        v += __shfl_xor(v, 16, 64);
        v += __shfl_xor(v, 32, 64);
        if (lq == 0) atomicAdd(&rowsum[row0 + wr2 * 64 + ri * 16 + lm], v);
    }
}

// ---------------- K3: A write + out accumulate ----------------
// grid 512 = 128 rb x 4 cs; block tile 64r x (32 iters x 64c); wave = 32r x 32c (S) / 32r x 64h (U).
// LDS: ZC+ZCT+PT (45.1 KB) -> 3 blocks/CU. Bfr loaded once from global.
__global__ __launch_bounds__(256) void k_main(const ushort* __restrict__ Zb,
                                              const ushort* __restrict__ ZbT,
                                              const float* __restrict__ rowsum,
                                              float* __restrict__ outp,
                                              float* __restrict__ Ap) {
    __shared__ ushort ZC[64][136];
    __shared__ ushort ZCT[128][72];  // Z tile [h][c] for U B-operand
    __shared__ ushort PT[64][72];    // normalized A tile bf16, [r][c]
    int tid = threadIdx.x, lane = tid & 63, wave = tid >> 6;
    int lm = lane & 15, lq = lane >> 4;
    int rb = blockIdx.x >> 2, cs = blockIdx.x & 3;
    int row0 = rb * 64, colb = cs * 2048;
    int wr2 = wave >> 1, wc2 = wave & 1;
    v8s Bfr[2][4];  // reg-cached row frags, one-time global load
#pragma unroll
    for (int ri = 0; ri < 2; ++ri)
#pragma unroll
        for (int ks = 0; ks < 4; ++ks)
            Bfr[ri][ks] =
                *(const v8s*)(Zb + (size_t)(row0 + wr2 * 32 + ri * 16 + lm) * HD + ks * 32 + lq * 8);
    float rsv[2];
#pragma unroll
    for (int ri = 0; ri < 2; ++ri)
        rsv[ri] = 1.0f / (rowsum[row0 + wr2 * 32 + ri * 16 + lm] + 1e-6f);
    v4f U[2][4];
#pragma unroll
    for (int ri = 0; ri < 2; ++ri)
#pragma unroll
        for (int hi = 0; hi < 4; ++hi) U[ri][hi] = (v4f){0.f, 0.f, 0.f, 0.f};

    for (int it = 0; it < 32; ++it) {
        int c0 = colb + it * 64;
        __syncthreads();  // prev MFMA2 reads of ZCT/PT done
#pragma unroll
        for (int t = 0; t < 4; ++t) {
            int idx = tid + t * 256;
            int r = idx >> 4, c8 = (idx & 15) * 8;
            *(uint4*)&ZC[r][c8] = *(const uint4*)(Zb + (size_t)(c0 + r) * HD + c8);
        }
#pragma unroll
        for (int t = 0; t < 4; ++t) {
            int idx = tid + t * 256;
            int hh = idx >> 3, cc8 = (idx & 7) * 8;
            *(uint4*)&ZCT[hh][cc8] = *(const uint4*)(ZbT + (size_t)hh * NR + c0 + cc8);
        }
        __syncthreads();
        // S^T = (ZC as A) x (row frags as B): D[m=c][n=r] -> lane: r=lm, c=lq*4+reg
#pragma unroll
        for (int ci = 0; ci < 2; ++ci) {
            v8s Af[4];
#pragma unroll
            for (int ks = 0; ks < 4; ++ks)
                Af[ks] = *(const v8s*)&ZC[wc2 * 32 + ci * 16 + lm][ks * 32 + lq * 8];
            v4f S0 = {0.f, 0.f, 0.f, 0.f}, S1 = {0.f, 0.f, 0.f, 0.f};
#pragma unroll
            for (int ks = 0; ks < 4; ++ks) {
                S0 = __builtin_amdgcn_mfma_f32_16x16x32_bf16(Af[ks], Bfr[0][ks], S0, 0, 0, 0);
                S1 = __builtin_amdgcn_mfma_f32_16x16x32_bf16(Af[ks], Bfr[1][ks], S1, 0, 0, 0);
            }
            int cb = wc2 * 32 + ci * 16 + lq * 4;
            {
                int r = wr2 * 32 + lm;
                v4f av;
                av[0] = fmaxf(S0[0], 0.f) * rsv[0]; av[1] = fmaxf(S0[1], 0.f) * rsv[0];
                av[2] = fmaxf(S0[2], 0.f) * rsv[0]; av[3] = fmaxf(S0[3], 0.f) * rsv[0];
                __builtin_nontemporal_store(av, (v4f*)(Ap + (size_t)(row0 + r) * NR + c0 + cb));
                *(uint2*)&PT[r][cb] = make_uint2(pk2(av[0], av[1]), pk2(av[2], av[3]));
            }
            {
                int r = wr2 * 32 + 16 + lm;
                v4f av;
                av[0] = fmaxf(S1[0], 0.f) * rsv[1]; av[1] = fmaxf(S1[1], 0.f) * rsv[1];
                av[2] = fmaxf(S1[2], 0.f) * rsv[1]; av[3] = fmaxf(S1[3], 0.f) * rsv[1];
                __builtin_nontemporal_store(av, (v4f*)(Ap + (size_t)(row0 + r) * NR + c0 + cb));
                *(uint2*)&PT[r][cb] = make_uint2(pk2(av[0], av[1]), pk2(av[2], av[3]));
            }
        }
        __syncthreads();
        // U[r][h] += P[r][c] * Z[c][h]; A = PT frag, B = ZCT frag
#pragma unroll
        for (int ks = 0; ks < 2; ++ks) {
            v8s P0 = *(const v8s*)&PT[wr2 * 32 + lm][ks * 32 + lq * 8];
            v8s P1 = *(const v8s*)&PT[wr2 * 32 + 16 + lm][ks * 32 + lq * 8];
#pragma unroll
            for (int hi = 0; hi < 4; ++hi) {
                v8s Bz = *(const v8s*)&ZCT[wc2 * 64 + hi * 16 + lm][ks * 32 + lq * 8];
                U[0][hi] = __builtin_amdgcn_mfma_f32_16x16x32_bf16(P0, Bz, U[0][hi], 0, 0, 0);
                U[1][hi] = __builtin_amdgcn_mfma_f32_16x16x32_bf16(P1, Bz, U[1][hi], 0, 0, 0);
            }
        }
    }
#pragma unroll
    for (int ri = 0; ri < 2; ++ri)
#pragma unroll
        for (int hi = 0; hi < 4; ++hi)
#pragma unroll
            for (int j = 0; j < 4; ++j)
                atomicAdd(&outp[(size_t)(row0 + wr2 * 32 + ri * 16 + lq * 4 + j) * HD +
                                wc2 * 64 + hi * 16 + lm],
                          U[ri][hi][j]);
}

extern "C" void kernel_launch(void* const* d_in, const int* in_sizes, int n_in,
                              void* d_out, int out_size, void* d_ws, size_t ws_size,
                              hipStream_t stream) {
    (void)in_sizes; (void)n_in; (void)out_size; (void)ws_size;
    const float* X = (const float*)d_in[0];
    const float* W = (const float*)d_in[1];
    float* outp = (float*)d_out;
    float* Ap = outp + (size_t)NR * HD;  // A follows out in d_out
    char* ws = (char*)d_ws;
    ushort* Zb = (ushort*)ws;                                 // 2 MB
    ushort* ZbT = (ushort*)(ws + (size_t)NR * HD * 2);        // 2 MB
    float* rowsum = (float*)(ws + (size_t)NR * HD * 4);       // 32 KB

    (void)hipMemsetAsync(outp, 0, (size_t)NR * HD * sizeof(float), stream);
    (void)hipMemsetAsync(rowsum, 0, NR * sizeof(float), stream);
    k_z<<<dim3(NR / 32), dim3(256), 0, stream>>>(X, W, Zb, ZbT);
    k_rowsum<<<dim3(512), dim3(256), 0, stream>>>(Zb, rowsum);
    k_main<<<dim3(512), dim3(256), 0, stream>>>(Zb, ZbT, rowsum, outp, Ap);
}